// Round 15
// baseline (113.951 us; speedup 1.0000x reference)
//
#include <hip/hip_runtime.h>
#include <hip/hip_bf16.h>

typedef short short8 __attribute__((ext_vector_type(8)));
typedef float f32x4 __attribute__((ext_vector_type(4)));

#define NGRAPH 1024
#define NPG    128     // nodes per graph
#define INF    512
#define NHEAD  8
#define CH     32      // chunk nodes

__device__ __forceinline__ ushort f2b(float f){
  __hip_bfloat16 h(f);
  union { __hip_bfloat16 h; ushort u; } v; v.h = h; return v.u;
}
__device__ __forceinline__ float b2f_lo(unsigned u){
  union { unsigned u; float f; } v; v.u = u << 16; return v.f;
}
__device__ __forceinline__ float b2f_hi(unsigned u){
  union { unsigned u; float f; } v; v.u = u & 0xffff0000u; return v.f;
}

// kq[h][f] = sum_d query[h,d]*key_w[h*64+d, f]   (key bias cancels in softmax)
__global__ void k_kq(const float* __restrict__ q, const float* __restrict__ kw,
                     float* __restrict__ kq){
  int h = blockIdx.x, t = threadIdx.x;   // 8 blocks x 512 threads
  float s = 0.f;
  #pragma unroll 8
  for(int d = 0; d < 64; d++)
    s += q[h*64 + d] * kw[(size_t)(h*64 + d)*INF + t];
  kq[h*INF + t] = s;
}

// K1 (R12-proven, best): CH=32, online-rescale softmax, half-chunk register
// prefetch at top of phase C, embedded weight cvt.  1024 blocks x 128 thr,
// ~33KB LDS, 4 blocks/CU.
__global__ __launch_bounds__(128, 2) void k_graph(
    const float* __restrict__ x, const float* __restrict__ kq,
    const float* __restrict__ vw, const float* __restrict__ ow,
    const float* __restrict__ gw,
    ushort* __restrict__ vwb, ushort* __restrict__ owb, ushort* __restrict__ gwb,
    ushort* __restrict__ xw_b, float* __restrict__ avg_f, ushort* __restrict__ avg_b){
  __shared__ __align__(16) ushort xs[CH*INF];    // 32KB bf16, byte ^= ((node&7)<<4)
  __shared__ __align__(16) float  sc[CH*NHEAD];  // scores -> scaled weights
  __shared__ float mEf[3*NHEAD];                 // M[h], E[h], f_old[h]

  const int t = threadIdx.x, lane = t & 63, w = t >> 6;
  const int col = lane & 15, kg = lane >> 4;
  const int g = blockIdx.x;
  const int node = w*16 + col;                   // 0..31

  // ---- embedded weight cvt: block g -> elems [g*1024, g*1024+1024) ----
  {
    int idx = g*1024 + t*8;            // 1M elems total: vw | ow | gw
    const float* src; ushort* dst; int off;
    if(idx < 262144){ src = vw; dst = vwb; off = idx; }
    else if(idx < 524288){ src = ow; dst = owb; off = idx - 262144; }
    else { src = gw; dst = gwb; off = idx - 524288; }
    float4 a = *(const float4*)(src + off);
    float4 b = *(const float4*)(src + off + 4);
    short8 v;
    v[0]=(short)f2b(a.x); v[1]=(short)f2b(a.y); v[2]=(short)f2b(a.z); v[3]=(short)f2b(a.w);
    v[4]=(short)f2b(b.x); v[5]=(short)f2b(b.y); v[6]=(short)f2b(b.z); v[7]=(short)f2b(b.w);
    *(short8*)(dst + off) = v;
  }

  short8 bfrag[16];
  {
    const bool ok = (col < 8);
    const float* kqr = kq + col*INF;
    #pragma unroll
    for(int ks = 0; ks < 16; ks++){
      short8 v = short8{0,0,0,0,0,0,0,0};
      if(ok){
        float4 p0 = *(const float4*)(kqr + ks*32 + kg*8);
        float4 p1 = *(const float4*)(kqr + ks*32 + kg*8 + 4);
        v[0]=(short)f2b(p0.x); v[1]=(short)f2b(p0.y); v[2]=(short)f2b(p0.z); v[3]=(short)f2b(p0.w);
        v[4]=(short)f2b(p1.x); v[5]=(short)f2b(p1.y); v[6]=(short)f2b(p1.z); v[7]=(short)f2b(p1.w);
      }
      bfrag[ks] = v;
    }
  }

  if(t < NHEAD){ mEf[t] = -1e30f; mEf[NHEAD + t] = 0.f; }

  // prefetch: first half (ks 0..7) of chunk 0 for this thread's node slice
  float4 pf[16];
  {
    const float* xr = x + (size_t)(g*NPG + node)*INF + kg*8;
    #pragma unroll
    for(int ks = 0; ks < 8; ks++){
      pf[2*ks]     = *(const float4*)(xr + ks*32);
      pf[2*ks + 1] = *(const float4*)(xr + ks*32 + 4);
    }
  }

  float2 acc2[NHEAD][2];        // [h]{cols 4t,4t+1}{cols 4t+2,4t+3}
  #pragma unroll
  for(int h = 0; h < NHEAD; h++){
    acc2[h][0] = float2{0.f, 0.f}; acc2[h][1] = float2{0.f, 0.f};
  }
  float2 cs01 = {0.f, 0.f}, cs23 = {0.f, 0.f};

  for(int c = 0; c < 4; c++){
    // ---- phase A: MFMA scores + stage bf16 (ks<8 from pf regs, ks>=8 load) ----
    {
      const float* xr = x + (size_t)(g*NPG + c*CH + node)*INF + kg*8;
      f32x4 sacc = {0.f,0.f,0.f,0.f};
      #pragma unroll
      for(int ks = 0; ks < 16; ks++){
        float4 a, b;
        if(ks < 8){ a = pf[2*ks]; b = pf[2*ks + 1]; }
        else { a = *(const float4*)(xr + ks*32); b = *(const float4*)(xr + ks*32 + 4); }
        short8 af;
        af[0]=(short)f2b(a.x); af[1]=(short)f2b(a.y); af[2]=(short)f2b(a.z); af[3]=(short)f2b(a.w);
        af[4]=(short)f2b(b.x); af[5]=(short)f2b(b.y); af[6]=(short)f2b(b.z); af[7]=(short)f2b(b.w);
        *(short8*)((char*)xs + node*1024 + ((ks*64 + kg*16) ^ ((node & 7) << 4))) = af;
        sacc = __builtin_amdgcn_mfma_f32_16x16x32_bf16(af, bfrag[ks], sacc, 0, 0, 0);
      }
      if(col < 8){
        #pragma unroll
        for(int r = 0; r < 4; r++)
          sc[(w*16 + kg*4 + r)*NHEAD + col] = sacc[r];  // C/D: row=(l>>4)*4+r, col=l&15
      }
    }
    __syncthreads();

    // ---- phase B: local stats over 32 nodes/head, online merge ----
    {
      int h = t >> 4, s = t & 15;
      float v[2]; float m = -1e30f;
      #pragma unroll
      for(int i = 0; i < 2; i++){ v[i] = sc[(s + 16*i)*NHEAD + h]; m = fmaxf(m, v[i]); }
      #pragma unroll
      for(int msk = 1; msk < 16; msk <<= 1) m = fmaxf(m, __shfl_xor(m, msk));
      float es = 0.f;
      #pragma unroll
      for(int i = 0; i < 2; i++){ v[i] = __expf(v[i] - m); es += v[i]; }
      #pragma unroll
      for(int msk = 1; msk < 16; msk <<= 1) es += __shfl_xor(es, msk);
      float M = mEf[h], E = mEf[NHEAD + h];
      float Mn = fmaxf(M, m);
      float f_old = __expf(M - Mn), f_new = __expf(m - Mn);
      #pragma unroll
      for(int i = 0; i < 2; i++) sc[(s + 16*i)*NHEAD + h] = v[i]*f_new;
      if(s == 0){
        mEf[h] = Mn;
        mEf[NHEAD + h] = E*f_old + es*f_new;
        mEf[2*NHEAD + h] = f_old;
      }
    }
    __syncthreads();

    // ---- phase C: rescale, ISSUE next-chunk prefetch, weighted accumulate ----
    {
      float fo[NHEAD];
      #pragma unroll
      for(int h = 0; h < NHEAD; h++) fo[h] = mEf[2*NHEAD + h];
      #pragma unroll
      for(int h = 0; h < NHEAD; h++){
        acc2[h][0].x *= fo[h]; acc2[h][0].y *= fo[h];
        acc2[h][1].x *= fo[h]; acc2[h][1].y *= fo[h];
      }
      if(c < 3){
        const float* xn = x + (size_t)(g*NPG + (c+1)*CH + node)*INF + kg*8;
        #pragma unroll
        for(int ks = 0; ks < 8; ks++){
          pf[2*ks]     = *(const float4*)(xn + ks*32);
          pf[2*ks + 1] = *(const float4*)(xn + ks*32 + 4);
        }
      }
      #pragma unroll 4
      for(int n = 0; n < CH; n++){
        uint2 xv = *(const uint2*)((const char*)xs + n*1024 + ((8*t) ^ ((n & 7) << 4)));
        float2 x01 = {b2f_lo(xv.x), b2f_hi(xv.x)};
        float2 x23 = {b2f_lo(xv.y), b2f_hi(xv.y)};
        float4 w0 = *(float4*)(sc + n*NHEAD);
        float4 w1 = *(float4*)(sc + n*NHEAD + 4);
        float wv[8] = {w0.x, w0.y, w0.z, w0.w, w1.x, w1.y, w1.z, w1.w};
        #pragma unroll
        for(int h = 0; h < NHEAD; h++){
          acc2[h][0].x = fmaf(wv[h], x01.x, acc2[h][0].x);
          acc2[h][0].y = fmaf(wv[h], x01.y, acc2[h][0].y);
          acc2[h][1].x = fmaf(wv[h], x23.x, acc2[h][1].x);
          acc2[h][1].y = fmaf(wv[h], x23.y, acc2[h][1].y);
        }
        cs01.x += x01.x; cs01.y += x01.y; cs23.x += x23.x; cs23.y += x23.y;
      }
    }
    __syncthreads();
  }

  // ---- epilogue: normalize, write xw + avg ----
  #pragma unroll
  for(int h = 0; h < NHEAD; h++){
    float einv = 1.0f / fmaxf(mEf[NHEAD + h], 1e-12f);
    float v0 = acc2[h][0].x*einv, v1 = acc2[h][0].y*einv;
    float v2 = acc2[h][1].x*einv, v3 = acc2[h][1].y*einv;
    uint2 pk = { (unsigned)f2b(v0) | ((unsigned)f2b(v1) << 16),
                 (unsigned)f2b(v2) | ((unsigned)f2b(v3) << 16) };
    *(uint2*)(xw_b + (size_t)g*4096 + h*INF + 4*t) = pk;
  }
  float am0 = cs01.x*(1.0f/128.0f), am1 = cs01.y*(1.0f/128.0f);
  float am2 = cs23.x*(1.0f/128.0f), am3 = cs23.y*(1.0f/128.0f);
  float4 av = {am0, am1, am2, am3};
  *(float4*)(avg_f + (size_t)g*INF + 4*t) = av;
  uint2 pk = { (unsigned)f2b(am0) | ((unsigned)f2b(am1) << 16),
               (unsigned)f2b(am2) | ((unsigned)f2b(am3) << 16) };
  *(uint2*)(avg_b + (size_t)g*INF + 4*t) = pk;
}

// bf16 TN GEMM (R12-proven): 64x32 tiles, BK=64, double-buffered, grid (M/64, N/32).
__global__ __launch_bounds__(256, 4) void gemm_tn(
    const ushort* __restrict__ A1, const ushort* __restrict__ A2,
    int lda, int headmode,
    const ushort* __restrict__ Wt, int ldw,
    const float* __restrict__ bias,
    float* __restrict__ Cf, ushort* __restrict__ Cb,
    int ldc, int K, int ksplit){
  __shared__ ushort As[2][64*72];   // 144B row stride (64 k + 8 pad)
  __shared__ ushort Bs[2][32*72];
  const int t = threadIdx.x, lane = t & 63, w = t >> 6;
  const int m0 = blockIdx.x*64, n0 = blockIdx.y*32;
  const int aoff = headmode ? (blockIdx.y >> 1)*512 : 0;   // head = col/64
  const int col = lane & 15, kg = lane >> 4;
  const int ar = t >> 2, ak = (t & 3)*16;   // A: 64 rows x 4 chunks of 16
  const int br = t >> 3, bk = (t & 7)*8;    // B: 32 rows x 8 chunks of 8

  f32x4 acc[2];
  acc[0] = f32x4{0.f,0.f,0.f,0.f};
  acc[1] = f32x4{0.f,0.f,0.f,0.f};

  // preload kc=0
  const ushort* Ap0 = (0 < ksplit) ? A1 : A2;
  short8 va0 = *(const short8*)(Ap0 + (size_t)(m0 + ar)*lda + aoff + ak);
  short8 va1 = *(const short8*)(Ap0 + (size_t)(m0 + ar)*lda + aoff + ak + 8);
  short8 vb  = *(const short8*)(Wt + (size_t)(n0 + br)*ldw + bk);
  int buf = 0;
  for(int kc = 0; kc < K; kc += 64){
    *(short8*)((char*)&As[buf][0] + ar*144 + ak*2)      = va0;
    *(short8*)((char*)&As[buf][0] + ar*144 + ak*2 + 16) = va1;
    *(short8*)((char*)&Bs[buf][0] + br*144 + bk*2)      = vb;
    __syncthreads();
    if(kc + 64 < K){
      int kn = kc + 64;
      const ushort* Ap = (kn < ksplit) ? A1 : A2;
      int kl = (kn < ksplit) ? kn : kn - ksplit;
      va0 = *(const short8*)(Ap + (size_t)(m0 + ar)*lda + aoff + kl + ak);
      va1 = *(const short8*)(Ap + (size_t)(m0 + ar)*lda + aoff + kl + ak + 8);
      vb  = *(const short8*)(Wt + (size_t)(n0 + br)*ldw + kn + bk);
    }
    const int mr = (w & 1)*32, nc = (w >> 1)*16;
    #pragma unroll
    for(int kk = 0; kk < 2; kk++){
      short8 af0 = *(short8*)((char*)&As[buf][0] + (mr + col)*144      + kk*64 + kg*16);
      short8 af1 = *(short8*)((char*)&As[buf][0] + (mr + 16 + col)*144 + kk*64 + kg*16);
      short8 bf  = *(short8*)((char*)&Bs[buf][0] + (nc + col)*144      + kk*64 + kg*16);
      acc[0] = __builtin_amdgcn_mfma_f32_16x16x32_bf16(af0, bf, acc[0], 0,0,0);
      acc[1] = __builtin_amdgcn_mfma_f32_16x16x32_bf16(af1, bf, acc[1], 0,0,0);
    }
    buf ^= 1;
  }
  #pragma unroll
  for(int mi = 0; mi < 2; mi++)
    #pragma unroll
    for(int r = 0; r < 4; r++){
      int rr = m0 + (w & 1)*32 + mi*16 + kg*4 + r;
      int cc = n0 + (w >> 1)*16 + col;
      float vv = acc[mi][r] + bias[cc];
      if(Cf) Cf[(size_t)rr*ldc + cc] = vv;
      if(Cb) Cb[(size_t)rr*ldc + cc] = f2b(vv);
    }
}

// K_ZLN: z = [ctx|avg] @ gw^T + gb, then sigmoid-gate mix + LayerNorm. Fused,
// row-local: 64 blocks x 16 rows x 256 thr.  A staged once (1 barrier), B from
// global (L2-hot, 8 independent MFMA chains), LN epilogue in-block.
__global__ __launch_bounds__(256, 2) void k_zln(
    const ushort* __restrict__ ctxb, const ushort* __restrict__ avgb,
    const ushort* __restrict__ gwb, const float* __restrict__ gb,
    const float* __restrict__ ctxf, const float* __restrict__ avgf,
    const float* __restrict__ lnw, const float* __restrict__ lnb,
    float* __restrict__ out){
  __shared__ __align__(16) ushort As[16*1024];   // 32KB bf16, byte ^= ((row&7)<<4)
  __shared__ __align__(16) float  zf[16*512];    // 32KB f32
  const int t = threadIdx.x, lane = t & 63, w = t >> 6;
  const int col = lane & 15, kg = lane >> 4;
  const int r0 = blockIdx.x*16;

  // stage A = [ctx_b | avg_b] rows, swizzled (coalesced 16B per thread x 8)
  #pragma unroll
  for(int it = 0; it < 8; it++){
    int i = it*2048 + t*8;            // elem in 16x1024
    int row = i >> 10, k = i & 1023;
    short8 v;
    if(k < 512) v = *(const short8*)(ctxb + (size_t)(r0 + row)*512 + k);
    else        v = *(const short8*)(avgb + (size_t)(r0 + row)*512 + (k - 512));
    *(short8*)((char*)As + row*2048 + ((k*2) ^ ((row & 7) << 4))) = v;
  }
  __syncthreads();

  // z: wave w -> col-tiles w*8 .. w*8+7 (each 16 cols), K = 1024
  {
    f32x4 zacc[8];
    #pragma unroll
    for(int ni = 0; ni < 8; ni++) zacc[ni] = f32x4{0.f,0.f,0.f,0.f};
    for(int ks = 0; ks < 32; ks++){
      int kk = ks*32 + kg*8;
      short8 af = *(short8*)((char*)As + col*2048 + ((kk*2) ^ ((col & 7) << 4)));
      #pragma unroll
      for(int ni = 0; ni < 8; ni++){
        short8 bf = *(const short8*)(gwb + (size_t)((w*8 + ni)*16 + col)*1024 + kk);
        zacc[ni] = __builtin_amdgcn_mfma_f32_16x16x32_bf16(af, bf, zacc[ni], 0,0,0);
      }
    }
    #pragma unroll
    for(int ni = 0; ni < 8; ni++)
      #pragma unroll
      for(int r = 0; r < 4; r++){
        int row = kg*4 + r, cc = (w*8 + ni)*16 + col;
        zf[row*512 + cc] = zacc[ni][r] + gb[cc];
      }
  }
  __syncthreads();

  // mix + LayerNorm: thread (row=t>>4, j=t&15) owns cols {j, j+16, ..., j+496}
  {
    const int row = t >> 4, j = t & 15;
    float e[32];
    float s1 = 0.f, s2 = 0.f;
    #pragma unroll
    for(int i = 0; i < 32; i++){
      int cc = j + i*16;
      float zz = zf[row*512 + cc];
      float cv = ctxf[(size_t)(r0 + row)*512 + cc];
      float av = avgf[(size_t)(r0 + row)*512 + cc];
      float gg = 1.0f / (1.0f + __expf(-zz));
      float ee = gg*cv + (1.0f - gg)*av;
      e[i] = ee; s1 += ee; s2 += ee*ee;
    }
    #pragma unroll
    for(int msk = 1; msk < 16; msk <<= 1){
      s1 += __shfl_xor(s1, msk); s2 += __shfl_xor(s2, msk);
    }
    float mu = s1*(1.0f/512.0f);
    float var = s2*(1.0f/512.0f) - mu*mu;
    float rinv = rsqrtf(var + 1e-5f);
    #pragma unroll
    for(int i = 0; i < 32; i++){
      int cc = j + i*16;
      out[(size_t)(r0 + row)*512 + cc] = (e[i] - mu)*rinv*lnw[cc] + lnb[cc];
    }
  }
}

extern "C" void kernel_launch(void* const* d_in, const int* in_sizes, int n_in,
                              void* d_out, int out_size, void* d_ws, size_t ws_size,
                              hipStream_t stream){
  const float* x       = (const float*)d_in[0];
  // d_in[1] = batch: segments are exactly 128 consecutive nodes -> unused
  const float* query   = (const float*)d_in[2];
  const float* key_w   = (const float*)d_in[3];
  // d_in[4] = key_b: cancels in segment softmax
  const float* value_w = (const float*)d_in[5];
  const float* value_b = (const float*)d_in[6];
  const float* out_w   = (const float*)d_in[7];
  const float* out_b   = (const float*)d_in[8];
  const float* gate_w  = (const float*)d_in[9];
  const float* gate_b  = (const float*)d_in[10];
  const float* ln_w    = (const float*)d_in[11];
  const float* ln_b    = (const float*)d_in[12];
  float* out = (float*)d_out;

  char* ws = (char*)d_ws;
  float*  kq       = (float*) (ws + 0);         // 16 KB
  ushort* vw_b     = (ushort*)(ws + 16384);     // 512 KB
  ushort* ow_b     = (ushort*)(ws + 540672);    // 512 KB
  ushort* gw_b     = (ushort*)(ws + 1064960);   // 1 MB
  ushort* xw_b     = (ushort*)(ws + 2113536);   // 8 MB
  float*  avg_f    = (float*) (ws + 10502144);
  ushort* avg_b    = (ushort*)(ws + 12599296);
  ushort* pooled_b = (ushort*)(ws + 13647872);
  float*  ctx_f    = (float*) (ws + 14696448);
  ushort* ctx_b    = (ushort*)(ws + 16793600);

  k_kq<<<8, 512, 0, stream>>>(query, key_w, kq);

  k_graph<<<NGRAPH, 128, 0, stream>>>(x, kq, value_w, out_w, gate_w,
                                      vw_b, ow_b, gw_b, xw_b, avg_f, avg_b);

  // pooled[b][hd] = sum_f xw[b,h,f]*vw[hd,f] + vb[hd]   (per-head via headmode)
  gemm_tn<<<dim3(16, 16), 256, 0, stream>>>(xw_b, xw_b, 4096, 1, vw_b, 512, value_b,
                                            nullptr, pooled_b, 512, 512, 1 << 30);
  // ctx = pooled @ out_w^T + out_b
  gemm_tn<<<dim3(16, 16), 256, 0, stream>>>(pooled_b, pooled_b, 512, 0, ow_b, 512, out_b,
                                            ctx_f, ctx_b, 512, 512, 1 << 30);
  // z + gate mix + LayerNorm, fused row-local
  k_zln<<<64, 256, 0, stream>>>(ctx_b, avg_b, gw_b, gate_b, ctx_f, avg_f,
                                ln_w, ln_b, out);
}

// Round 16
// 94.323 us; speedup vs baseline: 1.2081x; 1.2081x over previous
//
#include <hip/hip_runtime.h>
#include <hip/hip_bf16.h>

typedef short short8 __attribute__((ext_vector_type(8)));
typedef float f32x4 __attribute__((ext_vector_type(4)));

#define NGRAPH 1024
#define NPG    128     // nodes per graph
#define INF    512
#define NHEAD  8
#define CH     32      // chunk nodes

__device__ __forceinline__ ushort f2b(float f){
  __hip_bfloat16 h(f);
  union { __hip_bfloat16 h; ushort u; } v; v.h = h; return v.u;
}
__device__ __forceinline__ float b2f_lo(unsigned u){
  union { unsigned u; float f; } v; v.u = u << 16; return v.f;
}
__device__ __forceinline__ float b2f_hi(unsigned u){
  union { unsigned u; float f; } v; v.u = u & 0xffff0000u; return v.f;
}

// kq[h][f] = sum_d query[h,d]*key_w[h*64+d, f]   (key bias cancels in softmax)
__global__ void k_kq(const float* __restrict__ q, const float* __restrict__ kw,
                     float* __restrict__ kq){
  int h = blockIdx.x, t = threadIdx.x;   // 8 blocks x 512 threads
  float s = 0.f;
  #pragma unroll 8
  for(int d = 0; d < 64; d++)
    s += q[h*64 + d] * kw[(size_t)(h*64 + d)*INF + t];
  kq[h*INF + t] = s;
}

// K1 (R12-proven, best): CH=32, online-rescale softmax, half-chunk register
// prefetch at top of phase C, embedded weight cvt.  1024 blocks x 128 thr,
// ~33KB LDS, 4 blocks/CU.
__global__ __launch_bounds__(128, 2) void k_graph(
    const float* __restrict__ x, const float* __restrict__ kq,
    const float* __restrict__ vw, const float* __restrict__ ow,
    const float* __restrict__ gw,
    ushort* __restrict__ vwb, ushort* __restrict__ owb, ushort* __restrict__ gwb,
    ushort* __restrict__ xw_b, float* __restrict__ avg_f, ushort* __restrict__ avg_b){
  __shared__ __align__(16) ushort xs[CH*INF];    // 32KB bf16, byte ^= ((node&7)<<4)
  __shared__ __align__(16) float  sc[CH*NHEAD];  // scores -> scaled weights
  __shared__ float mEf[3*NHEAD];                 // M[h], E[h], f_old[h]

  const int t = threadIdx.x, lane = t & 63, w = t >> 6;
  const int col = lane & 15, kg = lane >> 4;
  const int g = blockIdx.x;
  const int node = w*16 + col;                   // 0..31

  // ---- embedded weight cvt: block g -> elems [g*1024, g*1024+1024) ----
  {
    int idx = g*1024 + t*8;            // 1M elems total: vw | ow | gw
    const float* src; ushort* dst; int off;
    if(idx < 262144){ src = vw; dst = vwb; off = idx; }
    else if(idx < 524288){ src = ow; dst = owb; off = idx - 262144; }
    else { src = gw; dst = gwb; off = idx - 524288; }
    float4 a = *(const float4*)(src + off);
    float4 b = *(const float4*)(src + off + 4);
    short8 v;
    v[0]=(short)f2b(a.x); v[1]=(short)f2b(a.y); v[2]=(short)f2b(a.z); v[3]=(short)f2b(a.w);
    v[4]=(short)f2b(b.x); v[5]=(short)f2b(b.y); v[6]=(short)f2b(b.z); v[7]=(short)f2b(b.w);
    *(short8*)(dst + off) = v;
  }

  short8 bfrag[16];
  {
    const bool ok = (col < 8);
    const float* kqr = kq + col*INF;
    #pragma unroll
    for(int ks = 0; ks < 16; ks++){
      short8 v = short8{0,0,0,0,0,0,0,0};
      if(ok){
        float4 p0 = *(const float4*)(kqr + ks*32 + kg*8);
        float4 p1 = *(const float4*)(kqr + ks*32 + kg*8 + 4);
        v[0]=(short)f2b(p0.x); v[1]=(short)f2b(p0.y); v[2]=(short)f2b(p0.z); v[3]=(short)f2b(p0.w);
        v[4]=(short)f2b(p1.x); v[5]=(short)f2b(p1.y); v[6]=(short)f2b(p1.z); v[7]=(short)f2b(p1.w);
      }
      bfrag[ks] = v;
    }
  }

  if(t < NHEAD){ mEf[t] = -1e30f; mEf[NHEAD + t] = 0.f; }

  // prefetch: first half (ks 0..7) of chunk 0 for this thread's node slice
  float4 pf[16];
  {
    const float* xr = x + (size_t)(g*NPG + node)*INF + kg*8;
    #pragma unroll
    for(int ks = 0; ks < 8; ks++){
      pf[2*ks]     = *(const float4*)(xr + ks*32);
      pf[2*ks + 1] = *(const float4*)(xr + ks*32 + 4);
    }
  }

  float2 acc2[NHEAD][2];        // [h]{cols 4t,4t+1}{cols 4t+2,4t+3}
  #pragma unroll
  for(int h = 0; h < NHEAD; h++){
    acc2[h][0] = float2{0.f, 0.f}; acc2[h][1] = float2{0.f, 0.f};
  }
  float2 cs01 = {0.f, 0.f}, cs23 = {0.f, 0.f};

  for(int c = 0; c < 4; c++){
    // ---- phase A: MFMA scores + stage bf16 (ks<8 from pf regs, ks>=8 load) ----
    {
      const float* xr = x + (size_t)(g*NPG + c*CH + node)*INF + kg*8;
      f32x4 sacc = {0.f,0.f,0.f,0.f};
      #pragma unroll
      for(int ks = 0; ks < 16; ks++){
        float4 a, b;
        if(ks < 8){ a = pf[2*ks]; b = pf[2*ks + 1]; }
        else { a = *(const float4*)(xr + ks*32); b = *(const float4*)(xr + ks*32 + 4); }
        short8 af;
        af[0]=(short)f2b(a.x); af[1]=(short)f2b(a.y); af[2]=(short)f2b(a.z); af[3]=(short)f2b(a.w);
        af[4]=(short)f2b(b.x); af[5]=(short)f2b(b.y); af[6]=(short)f2b(b.z); af[7]=(short)f2b(b.w);
        *(short8*)((char*)xs + node*1024 + ((ks*64 + kg*16) ^ ((node & 7) << 4))) = af;
        sacc = __builtin_amdgcn_mfma_f32_16x16x32_bf16(af, bfrag[ks], sacc, 0, 0, 0);
      }
      if(col < 8){
        #pragma unroll
        for(int r = 0; r < 4; r++)
          sc[(w*16 + kg*4 + r)*NHEAD + col] = sacc[r];  // C/D: row=(l>>4)*4+r, col=l&15
      }
    }
    __syncthreads();

    // ---- phase B: local stats over 32 nodes/head, online merge ----
    {
      int h = t >> 4, s = t & 15;
      float v[2]; float m = -1e30f;
      #pragma unroll
      for(int i = 0; i < 2; i++){ v[i] = sc[(s + 16*i)*NHEAD + h]; m = fmaxf(m, v[i]); }
      #pragma unroll
      for(int msk = 1; msk < 16; msk <<= 1) m = fmaxf(m, __shfl_xor(m, msk));
      float es = 0.f;
      #pragma unroll
      for(int i = 0; i < 2; i++){ v[i] = __expf(v[i] - m); es += v[i]; }
      #pragma unroll
      for(int msk = 1; msk < 16; msk <<= 1) es += __shfl_xor(es, msk);
      float M = mEf[h], E = mEf[NHEAD + h];
      float Mn = fmaxf(M, m);
      float f_old = __expf(M - Mn), f_new = __expf(m - Mn);
      #pragma unroll
      for(int i = 0; i < 2; i++) sc[(s + 16*i)*NHEAD + h] = v[i]*f_new;
      if(s == 0){
        mEf[h] = Mn;
        mEf[NHEAD + h] = E*f_old + es*f_new;
        mEf[2*NHEAD + h] = f_old;
      }
    }
    __syncthreads();

    // ---- phase C: rescale, ISSUE next-chunk prefetch, weighted accumulate ----
    {
      float fo[NHEAD];
      #pragma unroll
      for(int h = 0; h < NHEAD; h++) fo[h] = mEf[2*NHEAD + h];
      #pragma unroll
      for(int h = 0; h < NHEAD; h++){
        acc2[h][0].x *= fo[h]; acc2[h][0].y *= fo[h];
        acc2[h][1].x *= fo[h]; acc2[h][1].y *= fo[h];
      }
      if(c < 3){
        const float* xn = x + (size_t)(g*NPG + (c+1)*CH + node)*INF + kg*8;
        #pragma unroll
        for(int ks = 0; ks < 8; ks++){
          pf[2*ks]     = *(const float4*)(xn + ks*32);
          pf[2*ks + 1] = *(const float4*)(xn + ks*32 + 4);
        }
      }
      #pragma unroll 4
      for(int n = 0; n < CH; n++){
        uint2 xv = *(const uint2*)((const char*)xs + n*1024 + ((8*t) ^ ((n & 7) << 4)));
        float2 x01 = {b2f_lo(xv.x), b2f_hi(xv.x)};
        float2 x23 = {b2f_lo(xv.y), b2f_hi(xv.y)};
        float4 w0 = *(float4*)(sc + n*NHEAD);
        float4 w1 = *(float4*)(sc + n*NHEAD + 4);
        float wv[8] = {w0.x, w0.y, w0.z, w0.w, w1.x, w1.y, w1.z, w1.w};
        #pragma unroll
        for(int h = 0; h < NHEAD; h++){
          acc2[h][0].x = fmaf(wv[h], x01.x, acc2[h][0].x);
          acc2[h][0].y = fmaf(wv[h], x01.y, acc2[h][0].y);
          acc2[h][1].x = fmaf(wv[h], x23.x, acc2[h][1].x);
          acc2[h][1].y = fmaf(wv[h], x23.y, acc2[h][1].y);
        }
        cs01.x += x01.x; cs01.y += x01.y; cs23.x += x23.x; cs23.y += x23.y;
      }
    }
    __syncthreads();
  }

  // ---- epilogue: normalize, write xw + avg ----
  #pragma unroll
  for(int h = 0; h < NHEAD; h++){
    float einv = 1.0f / fmaxf(mEf[NHEAD + h], 1e-12f);
    float v0 = acc2[h][0].x*einv, v1 = acc2[h][0].y*einv;
    float v2 = acc2[h][1].x*einv, v3 = acc2[h][1].y*einv;
    uint2 pk = { (unsigned)f2b(v0) | ((unsigned)f2b(v1) << 16),
                 (unsigned)f2b(v2) | ((unsigned)f2b(v3) << 16) };
    *(uint2*)(xw_b + (size_t)g*4096 + h*INF + 4*t) = pk;
  }
  float am0 = cs01.x*(1.0f/128.0f), am1 = cs01.y*(1.0f/128.0f);
  float am2 = cs23.x*(1.0f/128.0f), am3 = cs23.y*(1.0f/128.0f);
  float4 av = {am0, am1, am2, am3};
  *(float4*)(avg_f + (size_t)g*INF + 4*t) = av;
  uint2 pk = { (unsigned)f2b(am0) | ((unsigned)f2b(am1) << 16),
               (unsigned)f2b(am2) | ((unsigned)f2b(am3) << 16) };
  *(uint2*)(avg_b + (size_t)g*INF + 4*t) = pk;
}

// bf16 TN GEMM (R12-proven): 64x32 tiles, BK=64, double-buffered, grid (M/64, N/32).
__global__ __launch_bounds__(256, 4) void gemm_tn(
    const ushort* __restrict__ A1, const ushort* __restrict__ A2,
    int lda, int headmode,
    const ushort* __restrict__ Wt, int ldw,
    const float* __restrict__ bias,
    float* __restrict__ Cf, ushort* __restrict__ Cb,
    int ldc, int K, int ksplit){
  __shared__ ushort As[2][64*72];   // 144B row stride (64 k + 8 pad)
  __shared__ ushort Bs[2][32*72];
  const int t = threadIdx.x, lane = t & 63, w = t >> 6;
  const int m0 = blockIdx.x*64, n0 = blockIdx.y*32;
  const int aoff = headmode ? (blockIdx.y >> 1)*512 : 0;   // head = col/64
  const int col = lane & 15, kg = lane >> 4;
  const int ar = t >> 2, ak = (t & 3)*16;   // A: 64 rows x 4 chunks of 16
  const int br = t >> 3, bk = (t & 7)*8;    // B: 32 rows x 8 chunks of 8

  f32x4 acc[2];
  acc[0] = f32x4{0.f,0.f,0.f,0.f};
  acc[1] = f32x4{0.f,0.f,0.f,0.f};

  // preload kc=0
  const ushort* Ap0 = (0 < ksplit) ? A1 : A2;
  short8 va0 = *(const short8*)(Ap0 + (size_t)(m0 + ar)*lda + aoff + ak);
  short8 va1 = *(const short8*)(Ap0 + (size_t)(m0 + ar)*lda + aoff + ak + 8);
  short8 vb  = *(const short8*)(Wt + (size_t)(n0 + br)*ldw + bk);
  int buf = 0;
  for(int kc = 0; kc < K; kc += 64){
    *(short8*)((char*)&As[buf][0] + ar*144 + ak*2)      = va0;
    *(short8*)((char*)&As[buf][0] + ar*144 + ak*2 + 16) = va1;
    *(short8*)((char*)&Bs[buf][0] + br*144 + bk*2)      = vb;
    __syncthreads();
    if(kc + 64 < K){
      int kn = kc + 64;
      const ushort* Ap = (kn < ksplit) ? A1 : A2;
      int kl = (kn < ksplit) ? kn : kn - ksplit;
      va0 = *(const short8*)(Ap + (size_t)(m0 + ar)*lda + aoff + kl + ak);
      va1 = *(const short8*)(Ap + (size_t)(m0 + ar)*lda + aoff + kl + ak + 8);
      vb  = *(const short8*)(Wt + (size_t)(n0 + br)*ldw + kn + bk);
    }
    const int mr = (w & 1)*32, nc = (w >> 1)*16;
    #pragma unroll
    for(int kk = 0; kk < 2; kk++){
      short8 af0 = *(short8*)((char*)&As[buf][0] + (mr + col)*144      + kk*64 + kg*16);
      short8 af1 = *(short8*)((char*)&As[buf][0] + (mr + 16 + col)*144 + kk*64 + kg*16);
      short8 bf  = *(short8*)((char*)&Bs[buf][0] + (nc + col)*144      + kk*64 + kg*16);
      acc[0] = __builtin_amdgcn_mfma_f32_16x16x32_bf16(af0, bf, acc[0], 0,0,0);
      acc[1] = __builtin_amdgcn_mfma_f32_16x16x32_bf16(af1, bf, acc[1], 0,0,0);
    }
    buf ^= 1;
  }
  #pragma unroll
  for(int mi = 0; mi < 2; mi++)
    #pragma unroll
    for(int r = 0; r < 4; r++){
      int rr = m0 + (w & 1)*32 + mi*16 + kg*4 + r;
      int cc = n0 + (w >> 1)*16 + col;
      float vv = acc[mi][r] + bias[cc];
      if(Cf) Cf[(size_t)rr*ldc + cc] = vv;
      if(Cb) Cb[(size_t)rr*ldc + cc] = f2b(vv);
    }
}

// K5: gate mix + LayerNorm.
__global__ __launch_bounds__(512, 2) void k5_epilogue(
    const float* __restrict__ z, const float* __restrict__ ctx,
    const float* __restrict__ avg, const float* __restrict__ lnw,
    const float* __restrict__ lnb, float* __restrict__ out){
  __shared__ float red[16];
  const int t = threadIdx.x, b = blockIdx.x;
  const size_t i = (size_t)b*INF + t;
  float zz = z[i], c = ctx[i], a = avg[i];
  float g = 1.0f / (1.0f + __expf(-zz));
  float e = g*c + (1.0f - g)*a;
  float s1 = e, s2 = e*e;
  #pragma unroll
  for(int m = 1; m < 64; m <<= 1){ s1 += __shfl_xor(s1, m); s2 += __shfl_xor(s2, m); }
  int wv = t >> 6;
  if((t & 63) == 0){ red[wv] = s1; red[8 + wv] = s2; }
  __syncthreads();
  float ts1 = 0.f, ts2 = 0.f;
  #pragma unroll
  for(int k = 0; k < 8; k++){ ts1 += red[k]; ts2 += red[8 + k]; }
  float mu = ts1 * (1.0f/512.0f);
  float var = ts2 * (1.0f/512.0f) - mu*mu;
  out[i] = (e - mu) * rsqrtf(var + 1e-5f) * lnw[t] + lnb[t];
}

extern "C" void kernel_launch(void* const* d_in, const int* in_sizes, int n_in,
                              void* d_out, int out_size, void* d_ws, size_t ws_size,
                              hipStream_t stream){
  const float* x       = (const float*)d_in[0];
  // d_in[1] = batch: segments are exactly 128 consecutive nodes -> unused
  const float* query   = (const float*)d_in[2];
  const float* key_w   = (const float*)d_in[3];
  // d_in[4] = key_b: cancels in segment softmax
  const float* value_w = (const float*)d_in[5];
  const float* value_b = (const float*)d_in[6];
  const float* out_w   = (const float*)d_in[7];
  const float* out_b   = (const float*)d_in[8];
  const float* gate_w  = (const float*)d_in[9];
  const float* gate_b  = (const float*)d_in[10];
  const float* ln_w    = (const float*)d_in[11];
  const float* ln_b    = (const float*)d_in[12];
  float* out = (float*)d_out;

  char* ws = (char*)d_ws;
  float*  kq       = (float*) (ws + 0);         // 16 KB
  ushort* vw_b     = (ushort*)(ws + 16384);     // 512 KB
  ushort* ow_b     = (ushort*)(ws + 540672);    // 512 KB
  ushort* gw_b     = (ushort*)(ws + 1064960);   // 1 MB
  ushort* xw_b     = (ushort*)(ws + 2113536);   // 8 MB
  float*  avg_f    = (float*) (ws + 10502144);
  ushort* avg_b    = (ushort*)(ws + 12599296);
  ushort* pooled_b = (ushort*)(ws + 13647872);
  float*  ctx_f    = (float*) (ws + 14696448);
  ushort* ctx_b    = (ushort*)(ws + 16793600);
  float*  z_f      = (float*) (ws + 17842176);

  k_kq<<<8, 512, 0, stream>>>(query, key_w, kq);

  k_graph<<<NGRAPH, 128, 0, stream>>>(x, kq, value_w, out_w, gate_w,
                                      vw_b, ow_b, gw_b, xw_b, avg_f, avg_b);

  // pooled[b][hd] = sum_f xw[b,h,f]*vw[hd,f] + vb[hd]   (per-head via headmode)
  gemm_tn<<<dim3(16, 16), 256, 0, stream>>>(xw_b, xw_b, 4096, 1, vw_b, 512, value_b,
                                            nullptr, pooled_b, 512, 512, 1 << 30);
  // ctx = pooled @ out_w^T + out_b
  gemm_tn<<<dim3(16, 16), 256, 0, stream>>>(pooled_b, pooled_b, 512, 0, ow_b, 512, out_b,
                                            ctx_f, ctx_b, 512, 512, 1 << 30);
  // z = [ctx | avg] @ gate_w^T + gate_b
  gemm_tn<<<dim3(16, 16), 256, 0, stream>>>(ctx_b, avg_b, 512, 0, gw_b, 1024, gate_b,
                                            z_f, nullptr, 512, 1024, 512);

  k5_epilogue<<<NGRAPH, 512, 0, stream>>>(z_f, ctx_f, avg_f, ln_w, ln_b, out);
}